// Round 5
// baseline (573.826 us; speedup 1.0000x reference)
//
#include <hip/hip_runtime.h>
#include <math.h>

#define N_USERS 50000
#define N_ITEMS 50000
#define N_NODES 100000
#define N_NODES_PAD 100032
#define EMB 64
#define N_LAYERS 3
#define N_EDGES 1600000
#define BATCH 16384
#define REG_C 1e-05f
#define SLOPE 0.01f
#define EPS_C 1e-12f

#define SCAN_CHUNK 256
#define NCHUNK ((N_NODES + SCAN_CHUNK - 1) / SCAN_CHUNK)   // 391

// val quantization: val in [0, 0.05) -> 15-bit fixed point packed above 17-bit col
#define VAL_ENC 655360.0f            // 32768 / 0.05
#define VAL_DEC (1.0f / 655360.0f)

__device__ __forceinline__ unsigned short f2bf(float f) {
    unsigned int b = __float_as_uint(f);
    return (unsigned short)((b + 0x7fffu + ((b >> 16) & 1u)) >> 16);   // RNE
}

// ---------------- ego init: concat(u_emb, i_emb) + bf16 mirror ----------------
__global__ void k_init_ego(const float* __restrict__ u_emb,
                           const float* __restrict__ i_emb,
                           float* __restrict__ ego,
                           unsigned short* __restrict__ ego_bf) {
    int idx = blockIdx.x * blockDim.x + threadIdx.x;   // float4 index
    const int n4 = N_NODES * EMB / 4;
    if (idx < n4) {
        const int u4 = N_USERS * EMB / 4;
        float4 v = (idx < u4) ? ((const float4*)u_emb)[idx]
                              : ((const float4*)i_emb)[idx - u4];
        ((float4*)ego)[idx] = v;
        ushort4 h;
        h.x = f2bf(v.x); h.y = f2bf(v.y); h.z = f2bf(v.z); h.w = f2bf(v.w);
        *(ushort4*)&ego_bf[(size_t)idx * 4] = h;
    }
}

// ---------------- CSR build ----------------
#define HIST_T ((N_EDGES + 3) / 4)   // 400000 threads, 4 edges each
__global__ void k_histo(const int* __restrict__ rows, int* __restrict__ counts) {
    int tid = blockIdx.x * blockDim.x + threadIdx.x;
    if (tid >= HIST_T) return;
    int r[4]; int nv = 0;
    #pragma unroll
    for (int j = 0; j < 4; ++j) {
        int e = tid + j * HIST_T;
        if (e < N_EDGES) r[nv++] = rows[e];
    }
    #pragma unroll
    for (int j = 0; j < 4; ++j)
        if (j < nv) atomicAdd(&counts[r[j]], 1);
}

__global__ void k_chunk_sum(const int* __restrict__ counts, int* __restrict__ partials) {
    __shared__ int s[SCAN_CHUNK];
    int i = blockIdx.x * SCAN_CHUNK + threadIdx.x;
    int v = (i < N_NODES) ? counts[i] : 0;
    s[threadIdx.x] = v;
    __syncthreads();
    for (int st = SCAN_CHUNK / 2; st > 0; st >>= 1) {
        if ((int)threadIdx.x < st) s[threadIdx.x] += s[threadIdx.x + st];
        __syncthreads();
    }
    if (threadIdx.x == 0) partials[blockIdx.x] = s[0];
}

__global__ void k_scan_partials(int* __restrict__ partials) {
    __shared__ int s[512];
    int t = threadIdx.x;
    int v = (t < NCHUNK) ? partials[t] : 0;
    s[t] = v;
    __syncthreads();
    for (int st = 1; st < 512; st <<= 1) {
        int add = (t >= st) ? s[t - st] : 0;
        __syncthreads();
        s[t] += add;
        __syncthreads();
    }
    if (t < NCHUNK) partials[t] = s[t] - v;   // exclusive
}

__global__ void k_chunk_scan(const int* __restrict__ counts,
                             const int* __restrict__ partials,
                             int* __restrict__ offsets,
                             int* __restrict__ cursor) {
    __shared__ int s[SCAN_CHUNK];
    int t = threadIdx.x;
    int i = blockIdx.x * SCAN_CHUNK + t;
    int v = (i < N_NODES) ? counts[i] : 0;
    s[t] = v;
    __syncthreads();
    for (int st = 1; st < SCAN_CHUNK; st <<= 1) {
        int add = (t >= st) ? s[t - st] : 0;
        __syncthreads();
        s[t] += add;
        __syncthreads();
    }
    int excl = s[t] - v + partials[blockIdx.x];
    if (i < N_NODES) { offsets[i] = excl; cursor[i] = excl; }
    if (blockIdx.x == 0 && t == 0) offsets[N_NODES] = N_EDGES;
}

// scatter packed (col | q<<17), 4 independent chains per thread for MLP
__global__ void k_scatter(const int* __restrict__ rows, const int* __restrict__ cols,
                          const float* __restrict__ vals,
                          int* __restrict__ cursor,
                          unsigned int* __restrict__ edge_pk) {
    int tid = blockIdx.x * blockDim.x + threadIdx.x;
    if (tid >= HIST_T) return;
    int r[4]; unsigned int pk[4]; int nv = 0;
    #pragma unroll
    for (int j = 0; j < 4; ++j) {
        int e = tid + j * HIST_T;
        if (e < N_EDGES) {
            r[nv] = rows[e];
            unsigned int q = __float2uint_rn(vals[e] * VAL_ENC);
            q = (q > 32767u) ? 32767u : q;
            pk[nv] = (unsigned int)cols[e] | (q << 17);
            ++nv;
        }
    }
    int pos[4];
    #pragma unroll
    for (int j = 0; j < 4; ++j)
        if (j < nv) pos[j] = atomicAdd(&cursor[r[j]], 1);
    #pragma unroll
    for (int j = 0; j < 4; ++j)
        if (j < nv) edge_pk[pos[j]] = pk[j];
}

// ---------------- per-layer: gather-based segment sum (bf16 rows) ----------------
// One wave per node; quarter-wave (16 lanes x 8B = 128B bf16 row) per edge, so a
// single global_load_dwordx2 gathers 4 edge-rows. Packed meta prefetched one
// iteration ahead; inactive slots use pk=0 (val 0, gather row 0, L1-resident).
__global__ __launch_bounds__(256) void k_edge_agg(const int* __restrict__ offsets,
                                                  const unsigned int* __restrict__ edge_pk,
                                                  const unsigned short* __restrict__ ego_bf,
                                                  float* __restrict__ wsacc) {
    int n = blockIdx.x * 4 + (threadIdx.x >> 6);   // one wave per node
    int lane = threadIdx.x & 63;
    int qw = lane >> 4;     // 0..3: which edge of the group of 4
    int sl = lane & 15;     // 0..15: 8B slot within the 128B row
    if (n >= N_NODES) return;
    int o0 = offsets[n], o1 = offsets[n + 1];
    int d = o1 - o0;
    int T = (d + 3) >> 2;
    float a0 = 0.f, a1 = 0.f, a2 = 0.f, a3 = 0.f;
    int e = o0 + qw;
    unsigned int pk = (e < o1) ? edge_pk[e] : 0u;
    for (int t = 0; t < T; ++t) {
        unsigned int cur = pk;
        int en = e + 4;
        pk = (en < o1) ? edge_pk[en] : 0u;   // prefetch next meta
        int c = (int)(cur & 0x1FFFFu);
        float v = (float)(cur >> 17) * VAL_DEC;
        uint2 r8 = *(const uint2*)&ego_bf[(size_t)c * EMB + sl * 4];
        float r0 = __uint_as_float(r8.x << 16);
        float r1 = __uint_as_float(r8.x & 0xffff0000u);
        float r2 = __uint_as_float(r8.y << 16);
        float r3 = __uint_as_float(r8.y & 0xffff0000u);
        a0 += v * r0; a1 += v * r1;
        a2 += v * r2; a3 += v * r3;
        e = en;
    }
    a0 += __shfl_xor(a0, 16, 64); a1 += __shfl_xor(a1, 16, 64);
    a2 += __shfl_xor(a2, 16, 64); a3 += __shfl_xor(a3, 16, 64);
    a0 += __shfl_xor(a0, 32, 64); a1 += __shfl_xor(a1, 32, 64);
    a2 += __shfl_xor(a2, 32, 64); a3 += __shfl_xor(a3, 32, 64);
    if (qw == 0) {
        float4 o = make_float4(a0, a1, a2, a3);
        *(float4*)&wsacc[(size_t)n * EMB + sl * 4] = o;
    }
}

// ---------------- per-layer transform: tiled f32 GEMM ----------------
// t = [ws | ws*ego] @ [W1^T ; W2^T] + b1 + b2 ; leaky-relu -> ego (+ bf16 mirror)
// BM=64 rows/block, all 64 cols, K=128 split in two 64-phases.
// __launch_bounds__(256,3): cap VGPR so the K-loop (unroll 2) cannot spill;
// LDS 48KB -> 3 blocks/CU, matching.
__global__ __launch_bounds__(256, 3) void k_transform(const float* __restrict__ wsacc,
                                                      float* __restrict__ ego,
                                                      unsigned short* __restrict__ ego_bf,
                                                      const float* __restrict__ W1,
                                                      const float* __restrict__ b1,
                                                      const float* __restrict__ W2,
                                                      const float* __restrict__ b2) {
    __shared__ float Xs[64 * 64];    // [r][k'] swizzled, one K-half at a time
    __shared__ float Ws[64 * 128];   // [c][kk'] swizzled, kk = 0..127 (W1 | W2)
    int tid = threadIdx.x;

    // stage Wcat: Ws[c][k] = W1[c][k], Ws[c][64+k] = W2[c][k]; swizzle k' = k ^ ((c>>2 & 7)<<2)
    for (int idx = tid; idx < 4096; idx += 256) {
        int c = idx >> 6, k = idx & 63;
        int s = ((c >> 2) & 7) << 2;
        Ws[c * 128 + (k ^ s)]        = W1[idx];
        Ws[c * 128 + 64 + (k ^ s)]   = W2[idx];   // (64+k)^s == 64 + (k^s)
    }

    int lane = tid & 63, wv = tid >> 6;
    int r0 = blockIdx.x * 64;
    int ty = tid >> 4;       // 0..15 : owns rows ty*4 .. ty*4+3
    int tx = tid & 15;       // 0..15 : owns cols tx*4 .. tx*4+3
    int sa = (ty & 7) << 2;  // row swizzle: (r>>2)&7 == ty&7 for r = ty*4+i
    int sb = (tx & 7) << 2;  // col-row swizzle for Ws rows c = tx*4+j

    float acc[4][4] = {};

    // ---- phase A: k = 0..63 with X = ws ----
    for (int r = wv; r < 64; r += 4) {
        float wsv = wsacc[(size_t)(r0 + r) * EMB + lane];
        int s = ((r >> 2) & 7) << 2;
        Xs[r * 64 + (lane ^ s)] = wsv;
    }
    __syncthreads();
    #pragma unroll 2
    for (int ko = 0; ko < 64; ko += 4) {
        float4 a[4], b[4];
        #pragma unroll
        for (int i = 0; i < 4; ++i)
            a[i] = *(const float4*)&Xs[(ty * 4 + i) * 64 + (ko ^ sa)];
        #pragma unroll
        for (int j = 0; j < 4; ++j)
            b[j] = *(const float4*)&Ws[(tx * 4 + j) * 128 + (ko ^ sb)];
        #pragma unroll
        for (int i = 0; i < 4; ++i)
            #pragma unroll
            for (int j = 0; j < 4; ++j)
                acc[i][j] += a[i].x * b[j].x + a[i].y * b[j].y
                           + a[i].z * b[j].z + a[i].w * b[j].w;
    }
    __syncthreads();

    // ---- phase B: k = 64..127 with X = ws*ego ----
    for (int r = wv; r < 64; r += 4) {
        size_t g = (size_t)(r0 + r) * EMB + lane;
        float v = wsacc[g] * ego[g];
        int s = ((r >> 2) & 7) << 2;
        Xs[r * 64 + (lane ^ s)] = v;
    }
    __syncthreads();
    #pragma unroll 2
    for (int ko = 0; ko < 64; ko += 4) {
        float4 a[4], b[4];
        #pragma unroll
        for (int i = 0; i < 4; ++i)
            a[i] = *(const float4*)&Xs[(ty * 4 + i) * 64 + (ko ^ sa)];
        #pragma unroll
        for (int j = 0; j < 4; ++j)
            b[j] = *(const float4*)&Ws[(tx * 4 + j) * 128 + 64 + (ko ^ sb)];
        #pragma unroll
        for (int i = 0; i < 4; ++i)
            #pragma unroll
            for (int j = 0; j < 4; ++j)
                acc[i][j] += a[i].x * b[j].x + a[i].y * b[j].y
                           + a[i].z * b[j].z + a[i].w * b[j].w;
    }

    // ---- epilogue: bias + leaky, write ego (f32) + ego_bf (bf16 mirror) ----
    float4 bb1 = *(const float4*)&b1[tx * 4];
    float4 bb2 = *(const float4*)&b2[tx * 4];
    float bias[4] = { bb1.x + bb2.x, bb1.y + bb2.y, bb1.z + bb2.z, bb1.w + bb2.w };
    #pragma unroll
    for (int i = 0; i < 4; ++i) {
        int r = r0 + ty * 4 + i;   // < N_NODES_PAD, buffer padded -> no guard
        float4 o;
        float t0 = acc[i][0] + bias[0]; o.x = (t0 >= 0.f) ? t0 : SLOPE * t0;
        float t1 = acc[i][1] + bias[1]; o.y = (t1 >= 0.f) ? t1 : SLOPE * t1;
        float t2 = acc[i][2] + bias[2]; o.z = (t2 >= 0.f) ? t2 : SLOPE * t2;
        float t3 = acc[i][3] + bias[3]; o.w = (t3 >= 0.f) ? t3 : SLOPE * t3;
        *(float4*)&ego[(size_t)r * EMB + tx * 4] = o;
        ushort4 h;
        h.x = f2bf(o.x); h.y = f2bf(o.y); h.z = f2bf(o.z); h.w = f2bf(o.w);
        *(ushort4*)&ego_bf[(size_t)r * EMB + tx * 4] = h;
    }
}

// ---------------- per-layer: batch gather + partial-loss accumulation ----------------
// acc layout: [0]=dot_up, [1]=dot_un, [2]=ssq_u, [3]=ssq_p, [4]=ssq_n ; each [BATCH]
__global__ __launch_bounds__(256) void k_batch_acc(const float* __restrict__ src,
                                                   const int* __restrict__ u,
                                                   const int* __restrict__ ii,
                                                   const int* __restrict__ jj,
                                                   float* __restrict__ acc,
                                                   int normalize) {
    int wid = (blockIdx.x * blockDim.x + threadIdx.x) >> 6;
    int lane = threadIdx.x & 63;
    if (wid >= BATCH) return;
    int nu = u[wid];
    int np_ = N_USERS + ii[wid];
    int nn = N_USERS + jj[wid];
    float eu = src[(size_t)nu * EMB + lane];
    float ep = src[(size_t)np_ * EMB + lane];
    float en = src[(size_t)nn * EMB + lane];
    float d_up = eu * ep, d_un = eu * en;
    float s_u = eu * eu, s_p = ep * ep, s_n = en * en;
    #pragma unroll
    for (int m = 32; m > 0; m >>= 1) {
        d_up += __shfl_xor(d_up, m, 64);
        d_un += __shfl_xor(d_un, m, 64);
        s_u  += __shfl_xor(s_u,  m, 64);
        s_p  += __shfl_xor(s_p,  m, 64);
        s_n  += __shfl_xor(s_n,  m, 64);
    }
    if (lane == 0) {
        if (normalize) {
            float inu = 1.f / fmaxf(sqrtf(s_u), EPS_C);
            float inp = 1.f / fmaxf(sqrtf(s_p), EPS_C);
            float inn = 1.f / fmaxf(sqrtf(s_n), EPS_C);
            d_up *= inu * inp;
            d_un *= inu * inn;
            s_u *= inu * inu;
            s_p *= inp * inp;
            s_n *= inn * inn;
        }
        acc[0 * BATCH + wid] += d_up;
        acc[1 * BATCH + wid] += d_un;
        acc[2 * BATCH + wid] += s_u;
        acc[3 * BATCH + wid] += s_p;
        acc[4 * BATCH + wid] += s_n;
    }
}

// ---------------- final scalar ----------------
__global__ __launch_bounds__(1024) void k_finalize(const float* __restrict__ acc,
                                                   float* __restrict__ out) {
    __shared__ float s1[1024], s2[1024];
    float ls = 0.f, l2 = 0.f;
    for (int b = threadIdx.x; b < BATCH; b += 1024) {
        float x = acc[0 * BATCH + b] - acc[1 * BATCH + b];
        ls += fminf(x, 0.f) - log1pf(expf(-fabsf(x)));
        l2 += acc[2 * BATCH + b] + acc[3 * BATCH + b] + acc[4 * BATCH + b];
    }
    s1[threadIdx.x] = ls; s2[threadIdx.x] = l2;
    __syncthreads();
    for (int st = 512; st > 0; st >>= 1) {
        if ((int)threadIdx.x < st) {
            s1[threadIdx.x] += s1[threadIdx.x + st];
            s2[threadIdx.x] += s2[threadIdx.x + st];
        }
        __syncthreads();
    }
    if (threadIdx.x == 0)
        out[0] = -s1[0] / (float)BATCH + REG_C * (s2[0] * 0.5f) / (float)BATCH;
}

extern "C" void kernel_launch(void* const* d_in, const int* in_sizes, int n_in,
                              void* d_out, int out_size, void* d_ws, size_t ws_size,
                              hipStream_t stream) {
    (void)in_sizes; (void)n_in; (void)out_size; (void)ws_size;
    const int*   u     = (const int*)d_in[0];
    const int*   ii    = (const int*)d_in[1];
    const int*   jj    = (const int*)d_in[2];
    const int*   rows  = (const int*)d_in[3];
    const int*   cols  = (const int*)d_in[4];
    const float* vals  = (const float*)d_in[5];
    const float* u_emb = (const float*)d_in[6];
    const float* i_emb = (const float*)d_in[7];
    const float* W1_w  = (const float*)d_in[8];
    const float* W1_b  = (const float*)d_in[9];
    const float* W2_w  = (const float*)d_in[10];
    const float* W2_b  = (const float*)d_in[11];
    float* out = (float*)d_out;

    // workspace carve-up (rows padded to N_NODES_PAD so transform tail needs no guards)
    char* p = (char*)d_ws;
    float*          ego     = (float*)p;          p += (size_t)N_NODES_PAD * EMB * 4;
    float*          wsacc   = (float*)p;          p += (size_t)N_NODES_PAD * EMB * 4;
    unsigned short* ego_bf  = (unsigned short*)p; p += (size_t)N_NODES_PAD * EMB * 2;
    unsigned int*   edge_pk = (unsigned int*)p;   p += (size_t)N_EDGES * 4;
    int*   counts   = (int*)p;    p += (size_t)N_NODES * 4;
    int*   offsets  = (int*)p;    p += (size_t)(N_NODES + 1) * 4;
    int*   cursor   = (int*)p;    p += (size_t)N_NODES * 4;
    int*   partials = (int*)p;    p += 512 * 4;
    float* acc      = (float*)p;  p += (size_t)5 * BATCH * 4;

    hipMemsetAsync(counts, 0, (size_t)N_NODES * 4, stream);
    hipMemsetAsync(acc, 0, (size_t)5 * BATCH * 4, stream);

    k_init_ego<<<(N_NODES * EMB / 4 + 255) / 256, 256, 0, stream>>>(u_emb, i_emb, ego, ego_bf);
    k_histo<<<(HIST_T + 255) / 256, 256, 0, stream>>>(rows, counts);
    k_chunk_sum<<<NCHUNK, SCAN_CHUNK, 0, stream>>>(counts, partials);
    k_scan_partials<<<1, 512, 0, stream>>>(partials);
    k_chunk_scan<<<NCHUNK, SCAN_CHUNK, 0, stream>>>(counts, partials, offsets, cursor);
    k_scatter<<<(HIST_T + 255) / 256, 256, 0, stream>>>(rows, cols, vals, cursor, edge_pk);

    // layer 0 contribution (raw ego, no normalization)
    k_batch_acc<<<BATCH * 64 / 256, 256, 0, stream>>>(ego, u, ii, jj, acc, 0);

    for (int k = 0; k < N_LAYERS; ++k) {
        k_edge_agg<<<(N_NODES + 3) / 4, 256, 0, stream>>>(offsets, edge_pk, ego_bf, wsacc);
        k_transform<<<(N_NODES + 63) / 64, 256, 0, stream>>>(wsacc, ego, ego_bf,
                                              W1_w + k * 4096, W1_b + k * 64,
                                              W2_w + k * 4096, W2_b + k * 64);
        k_batch_acc<<<BATCH * 64 / 256, 256, 0, stream>>>(ego, u, ii, jj, acc, 1);
    }
    k_finalize<<<1, 1024, 0, stream>>>(acc, out);
}

// Round 6
// 416.076 us; speedup vs baseline: 1.3791x; 1.3791x over previous
//
#include <hip/hip_runtime.h>
#include <math.h>

#define N_USERS 50000
#define N_ITEMS 50000
#define N_NODES 100000
#define N_NODES_PAD 100032
#define EMB 64
#define N_LAYERS 3
#define N_EDGES 1600000
#define BATCH 16384
#define REG_C 1e-05f
#define SLOPE 0.01f
#define EPS_C 1e-12f

// bucket sort: bucket = row >> 8 (256 rows per bucket)
#define NBUK 391                 // ceil(100000/256)
#define TILE_C 6144              // edges staged per block in k_bucket_scatter
#define SPK_MAX 4608             // per-bucket LDS capacity in k_bucket_sort (avg 4092, sigma 64)

// val quantization: val in [0, 0.05) -> 15-bit fixed point packed above 17-bit col
#define VAL_ENC 655360.0f        // 32768 / 0.05
#define VAL_DEC (1.0f / 655360.0f)

__device__ __forceinline__ unsigned short f2bf(float f) {
    unsigned int b = __float_as_uint(f);
    return (unsigned short)((b + 0x7fffu + ((b >> 16) & 1u)) >> 16);   // RNE
}

// ---------------- ego init: concat(u_emb, i_emb) + bf16 mirror ----------------
__global__ void k_init_ego(const float* __restrict__ u_emb,
                           const float* __restrict__ i_emb,
                           float* __restrict__ ego,
                           unsigned short* __restrict__ ego_bf) {
    int idx = blockIdx.x * blockDim.x + threadIdx.x;   // float4 index
    const int n4 = N_NODES * EMB / 4;
    if (idx < n4) {
        const int u4 = N_USERS * EMB / 4;
        float4 v = (idx < u4) ? ((const float4*)u_emb)[idx]
                              : ((const float4*)i_emb)[idx - u4];
        ((float4*)ego)[idx] = v;
        ushort4 h;
        h.x = f2bf(v.x); h.y = f2bf(v.y); h.z = f2bf(v.z); h.w = f2bf(v.w);
        *(ushort4*)&ego_bf[(size_t)idx * 4] = h;
    }
}

// ---------------- pass A: per-bucket histogram (LDS-staged) ----------------
__global__ __launch_bounds__(256) void k_buk_histo(const int* __restrict__ rows,
                                                   int* __restrict__ bukhist) {
    __shared__ int h[NBUK];
    for (int i = threadIdx.x; i < NBUK; i += 256) h[i] = 0;
    __syncthreads();
    int stride = gridDim.x * blockDim.x;
    for (int e = blockIdx.x * blockDim.x + threadIdx.x; e < N_EDGES; e += stride)
        atomicAdd(&h[rows[e] >> 8], 1);
    __syncthreads();
    for (int i = threadIdx.x; i < NBUK; i += 256)
        if (h[i]) atomicAdd(&bukhist[i], h[i]);
}

// ---------------- pass B: scan bucket bases ----------------
__global__ __launch_bounds__(512) void k_buk_scan(const int* __restrict__ bukhist,
                                                  int* __restrict__ bukbase,
                                                  int* __restrict__ bukcur) {
    __shared__ int s[512];
    int t = threadIdx.x;
    int v = (t < NBUK) ? bukhist[t] : 0;
    s[t] = v;
    __syncthreads();
    for (int st = 1; st < 512; st <<= 1) {
        int a = (t >= st) ? s[t - st] : 0;
        __syncthreads();
        s[t] += a;
        __syncthreads();
    }
    if (t < NBUK) { bukbase[t] = s[t] - v; bukcur[t] = s[t] - v; }
    if (t == 0) bukbase[NBUK] = N_EDGES;
}

// ---------------- pass C: LDS-staged bucket scatter (coalesced runs) ----------------
__global__ __launch_bounds__(512) void k_bucket_scatter(const int* __restrict__ rows,
                                                        const int* __restrict__ cols,
                                                        const float* __restrict__ vals,
                                                        int* __restrict__ bukcur,
                                                        uint2* __restrict__ bucketed) {
    __shared__ uint2 stage[TILE_C];
    __shared__ int hist[NBUK];
    __shared__ int lofs[NBUK];
    __shared__ int lcur[NBUK];
    __shared__ int gbase[NBUK];
    __shared__ int scan_s[512];
    int tid = threadIdx.x;
    int e0 = blockIdx.x * TILE_C;
    int n = min(TILE_C, N_EDGES - e0);

    for (int i = tid; i < NBUK; i += 512) hist[i] = 0;
    __syncthreads();
    for (int i = tid; i < n; i += 512) atomicAdd(&hist[rows[e0 + i] >> 8], 1);
    __syncthreads();
    // exclusive scan of hist
    int v = (tid < NBUK) ? hist[tid] : 0;
    scan_s[tid] = v;
    __syncthreads();
    for (int st = 1; st < 512; st <<= 1) {
        int a = (tid >= st) ? scan_s[tid - st] : 0;
        __syncthreads();
        scan_s[tid] += a;
        __syncthreads();
    }
    if (tid < NBUK) {
        int excl = scan_s[tid] - v;
        lofs[tid] = excl;
        lcur[tid] = excl;
        gbase[tid] = v ? atomicAdd(&bukcur[tid], v) : 0;   // one global atomic per bucket per block
    }
    __syncthreads();
    // bin edges into LDS, bucket-grouped
    for (int i = tid; i < n; i += 512) {
        int e = e0 + i;
        int r = rows[e];
        unsigned int q = __float2uint_rn(vals[e] * VAL_ENC);
        q = (q > 32767u) ? 32767u : q;
        unsigned int pk = (unsigned int)cols[e] | (q << 17);
        int pos = atomicAdd(&lcur[r >> 8], 1);
        stage[pos] = make_uint2(pk, (unsigned int)r);
    }
    __syncthreads();
    // contiguous run writes: element i belongs to bucket stage[i].y>>8
    for (int i = tid; i < n; i += 512) {
        uint2 w = stage[i];
        int b = w.y >> 8;
        bucketed[gbase[b] + (i - lofs[b])] = w;
    }
}

// ---------------- pass D: within-bucket sort -> final CSR (edge_pk, offsets) ----------------
__global__ __launch_bounds__(256) void k_bucket_sort(const int* __restrict__ bukbase,
                                                     const uint2* __restrict__ bucketed,
                                                     unsigned int* __restrict__ edge_pk,
                                                     int* __restrict__ offsets) {
    __shared__ int hist[256];
    __shared__ int lofs[256];
    __shared__ int lcur[256];
    __shared__ unsigned int spk[SPK_MAX];
    int b = blockIdx.x, tid = threadIdx.x;
    int s = bukbase[b], e = bukbase[b + 1];
    int cnt = e - s;
    int r0 = b << 8;
    int nrows = min(256, N_NODES - r0);

    hist[tid] = 0;
    __syncthreads();
    for (int i = tid; i < cnt; i += 256) atomicAdd(&hist[bucketed[s + i].y & 255u], 1);
    __syncthreads();
    int v = hist[tid];
    lofs[tid] = v;
    __syncthreads();
    for (int st = 1; st < 256; st <<= 1) {
        int a = (tid >= st) ? lofs[tid - st] : 0;
        __syncthreads();
        lofs[tid] += a;
        __syncthreads();
    }
    int excl = lofs[tid] - v;   // own-element read only; no race
    __syncthreads();
    lofs[tid] = excl;
    lcur[tid] = excl;
    if (tid < nrows) offsets[r0 + tid] = s + excl;
    if (b == NBUK - 1 && tid == 0) offsets[N_NODES] = N_EDGES;
    __syncthreads();

    if (cnt <= SPK_MAX) {
        for (int i = tid; i < cnt; i += 256) {
            uint2 w = bucketed[s + i];
            int p = atomicAdd(&lcur[w.y & 255u], 1);
            spk[p] = w.x;
        }
        __syncthreads();
        for (int i = tid; i < cnt; i += 256) edge_pk[s + i] = spk[i];   // coalesced
    } else {
        // overflow fallback (statistically unreachable): direct global scatter
        for (int i = tid; i < cnt; i += 256) {
            uint2 w = bucketed[s + i];
            int p = atomicAdd(&lcur[w.y & 255u], 1);
            edge_pk[s + p] = w.x;
        }
    }
}

// ---------------- per-layer: gather-based segment sum (bf16 rows) ----------------
// One wave per node; quarter-wave (16 lanes x 8B = 128B bf16 row) per edge, so a
// single global_load_dwordx2 gathers 4 edge-rows. Packed meta prefetched one
// iteration ahead; inactive slots use pk=0 (val 0, gather row 0, L1-resident).
__global__ __launch_bounds__(256) void k_edge_agg(const int* __restrict__ offsets,
                                                  const unsigned int* __restrict__ edge_pk,
                                                  const unsigned short* __restrict__ ego_bf,
                                                  float* __restrict__ wsacc) {
    int n = blockIdx.x * 4 + (threadIdx.x >> 6);   // one wave per node
    int lane = threadIdx.x & 63;
    int qw = lane >> 4;     // 0..3: which edge of the group of 4
    int sl = lane & 15;     // 0..15: 8B slot within the 128B row
    if (n >= N_NODES) return;
    int o0 = offsets[n], o1 = offsets[n + 1];
    int d = o1 - o0;
    int T = (d + 3) >> 2;
    float a0 = 0.f, a1 = 0.f, a2 = 0.f, a3 = 0.f;
    int e = o0 + qw;
    unsigned int pk = (e < o1) ? edge_pk[e] : 0u;
    for (int t = 0; t < T; ++t) {
        unsigned int cur = pk;
        int en = e + 4;
        pk = (en < o1) ? edge_pk[en] : 0u;   // prefetch next meta
        int c = (int)(cur & 0x1FFFFu);
        float v = (float)(cur >> 17) * VAL_DEC;
        uint2 r8 = *(const uint2*)&ego_bf[(size_t)c * EMB + sl * 4];
        float r0 = __uint_as_float(r8.x << 16);
        float r1 = __uint_as_float(r8.x & 0xffff0000u);
        float r2 = __uint_as_float(r8.y << 16);
        float r3 = __uint_as_float(r8.y & 0xffff0000u);
        a0 += v * r0; a1 += v * r1;
        a2 += v * r2; a3 += v * r3;
        e = en;
    }
    a0 += __shfl_xor(a0, 16, 64); a1 += __shfl_xor(a1, 16, 64);
    a2 += __shfl_xor(a2, 16, 64); a3 += __shfl_xor(a3, 16, 64);
    a0 += __shfl_xor(a0, 32, 64); a1 += __shfl_xor(a1, 32, 64);
    a2 += __shfl_xor(a2, 32, 64); a3 += __shfl_xor(a3, 32, 64);
    if (qw == 0) {
        float4 o = make_float4(a0, a1, a2, a3);
        *(float4*)&wsacc[(size_t)n * EMB + sl * 4] = o;
    }
}

// ---------------- per-layer transform: tiled f32 GEMM ----------------
// t = [ws | ws*ego] @ [W1^T ; W2^T] + b1 + b2 ; leaky-relu -> ego (+ bf16 mirror)
// BM=64 rows/block, all 64 cols, K=128 split in two 64-phases.
// __launch_bounds__(256,3): cap VGPR so the K-loop (unroll 2) cannot spill;
// LDS 48KB -> 3 blocks/CU, matching.
__global__ __launch_bounds__(256, 3) void k_transform(const float* __restrict__ wsacc,
                                                      float* __restrict__ ego,
                                                      unsigned short* __restrict__ ego_bf,
                                                      const float* __restrict__ W1,
                                                      const float* __restrict__ b1,
                                                      const float* __restrict__ W2,
                                                      const float* __restrict__ b2) {
    __shared__ float Xs[64 * 64];    // [r][k'] swizzled, one K-half at a time
    __shared__ float Ws[64 * 128];   // [c][kk'] swizzled, kk = 0..127 (W1 | W2)
    int tid = threadIdx.x;

    // stage Wcat: Ws[c][k] = W1[c][k], Ws[c][64+k] = W2[c][k]; swizzle k' = k ^ ((c>>2 & 7)<<2)
    for (int idx = tid; idx < 4096; idx += 256) {
        int c = idx >> 6, k = idx & 63;
        int s = ((c >> 2) & 7) << 2;
        Ws[c * 128 + (k ^ s)]        = W1[idx];
        Ws[c * 128 + 64 + (k ^ s)]   = W2[idx];   // (64+k)^s == 64 + (k^s)
    }

    int lane = tid & 63, wv = tid >> 6;
    int r0 = blockIdx.x * 64;
    int ty = tid >> 4;       // 0..15 : owns rows ty*4 .. ty*4+3
    int tx = tid & 15;       // 0..15 : owns cols tx*4 .. tx*4+3
    int sa = (ty & 7) << 2;  // row swizzle: (r>>2)&7 == ty&7 for r = ty*4+i
    int sb = (tx & 7) << 2;  // col-row swizzle for Ws rows c = tx*4+j

    float acc[4][4] = {};

    // ---- phase A: k = 0..63 with X = ws ----
    for (int r = wv; r < 64; r += 4) {
        float wsv = wsacc[(size_t)(r0 + r) * EMB + lane];
        int s = ((r >> 2) & 7) << 2;
        Xs[r * 64 + (lane ^ s)] = wsv;
    }
    __syncthreads();
    #pragma unroll 2
    for (int ko = 0; ko < 64; ko += 4) {
        float4 a[4], b[4];
        #pragma unroll
        for (int i = 0; i < 4; ++i)
            a[i] = *(const float4*)&Xs[(ty * 4 + i) * 64 + (ko ^ sa)];
        #pragma unroll
        for (int j = 0; j < 4; ++j)
            b[j] = *(const float4*)&Ws[(tx * 4 + j) * 128 + (ko ^ sb)];
        #pragma unroll
        for (int i = 0; i < 4; ++i)
            #pragma unroll
            for (int j = 0; j < 4; ++j)
                acc[i][j] += a[i].x * b[j].x + a[i].y * b[j].y
                           + a[i].z * b[j].z + a[i].w * b[j].w;
    }
    __syncthreads();

    // ---- phase B: k = 64..127 with X = ws*ego ----
    for (int r = wv; r < 64; r += 4) {
        size_t g = (size_t)(r0 + r) * EMB + lane;
        float v = wsacc[g] * ego[g];
        int s = ((r >> 2) & 7) << 2;
        Xs[r * 64 + (lane ^ s)] = v;
    }
    __syncthreads();
    #pragma unroll 2
    for (int ko = 0; ko < 64; ko += 4) {
        float4 a[4], b[4];
        #pragma unroll
        for (int i = 0; i < 4; ++i)
            a[i] = *(const float4*)&Xs[(ty * 4 + i) * 64 + (ko ^ sa)];
        #pragma unroll
        for (int j = 0; j < 4; ++j)
            b[j] = *(const float4*)&Ws[(tx * 4 + j) * 128 + 64 + (ko ^ sb)];
        #pragma unroll
        for (int i = 0; i < 4; ++i)
            #pragma unroll
            for (int j = 0; j < 4; ++j)
                acc[i][j] += a[i].x * b[j].x + a[i].y * b[j].y
                           + a[i].z * b[j].z + a[i].w * b[j].w;
    }

    // ---- epilogue: bias + leaky, write ego (f32) + ego_bf (bf16 mirror) ----
    float4 bb1 = *(const float4*)&b1[tx * 4];
    float4 bb2 = *(const float4*)&b2[tx * 4];
    float bias[4] = { bb1.x + bb2.x, bb1.y + bb2.y, bb1.z + bb2.z, bb1.w + bb2.w };
    #pragma unroll
    for (int i = 0; i < 4; ++i) {
        int r = r0 + ty * 4 + i;   // < N_NODES_PAD, buffer padded -> no guard
        float4 o;
        float t0 = acc[i][0] + bias[0]; o.x = (t0 >= 0.f) ? t0 : SLOPE * t0;
        float t1 = acc[i][1] + bias[1]; o.y = (t1 >= 0.f) ? t1 : SLOPE * t1;
        float t2 = acc[i][2] + bias[2]; o.z = (t2 >= 0.f) ? t2 : SLOPE * t2;
        float t3 = acc[i][3] + bias[3]; o.w = (t3 >= 0.f) ? t3 : SLOPE * t3;
        *(float4*)&ego[(size_t)r * EMB + tx * 4] = o;
        ushort4 h;
        h.x = f2bf(o.x); h.y = f2bf(o.y); h.z = f2bf(o.z); h.w = f2bf(o.w);
        *(ushort4*)&ego_bf[(size_t)r * EMB + tx * 4] = h;
    }
}

// ---------------- per-layer: batch gather + partial-loss accumulation ----------------
// acc layout: [0]=dot_up, [1]=dot_un, [2]=ssq_u, [3]=ssq_p, [4]=ssq_n ; each [BATCH]
__global__ __launch_bounds__(256) void k_batch_acc(const float* __restrict__ src,
                                                   const int* __restrict__ u,
                                                   const int* __restrict__ ii,
                                                   const int* __restrict__ jj,
                                                   float* __restrict__ acc,
                                                   int normalize) {
    int wid = (blockIdx.x * blockDim.x + threadIdx.x) >> 6;
    int lane = threadIdx.x & 63;
    if (wid >= BATCH) return;
    int nu = u[wid];
    int np_ = N_USERS + ii[wid];
    int nn = N_USERS + jj[wid];
    float eu = src[(size_t)nu * EMB + lane];
    float ep = src[(size_t)np_ * EMB + lane];
    float en = src[(size_t)nn * EMB + lane];
    float d_up = eu * ep, d_un = eu * en;
    float s_u = eu * eu, s_p = ep * ep, s_n = en * en;
    #pragma unroll
    for (int m = 32; m > 0; m >>= 1) {
        d_up += __shfl_xor(d_up, m, 64);
        d_un += __shfl_xor(d_un, m, 64);
        s_u  += __shfl_xor(s_u,  m, 64);
        s_p  += __shfl_xor(s_p,  m, 64);
        s_n  += __shfl_xor(s_n,  m, 64);
    }
    if (lane == 0) {
        if (normalize) {
            float inu = 1.f / fmaxf(sqrtf(s_u), EPS_C);
            float inp = 1.f / fmaxf(sqrtf(s_p), EPS_C);
            float inn = 1.f / fmaxf(sqrtf(s_n), EPS_C);
            d_up *= inu * inp;
            d_un *= inu * inn;
            s_u *= inu * inu;
            s_p *= inp * inp;
            s_n *= inn * inn;
        }
        acc[0 * BATCH + wid] += d_up;
        acc[1 * BATCH + wid] += d_un;
        acc[2 * BATCH + wid] += s_u;
        acc[3 * BATCH + wid] += s_p;
        acc[4 * BATCH + wid] += s_n;
    }
}

// ---------------- final scalar ----------------
__global__ __launch_bounds__(1024) void k_finalize(const float* __restrict__ acc,
                                                   float* __restrict__ out) {
    __shared__ float s1[1024], s2[1024];
    float ls = 0.f, l2 = 0.f;
    for (int b = threadIdx.x; b < BATCH; b += 1024) {
        float x = acc[0 * BATCH + b] - acc[1 * BATCH + b];
        ls += fminf(x, 0.f) - log1pf(expf(-fabsf(x)));
        l2 += acc[2 * BATCH + b] + acc[3 * BATCH + b] + acc[4 * BATCH + b];
    }
    s1[threadIdx.x] = ls; s2[threadIdx.x] = l2;
    __syncthreads();
    for (int st = 512; st > 0; st >>= 1) {
        if ((int)threadIdx.x < st) {
            s1[threadIdx.x] += s1[threadIdx.x + st];
            s2[threadIdx.x] += s2[threadIdx.x + st];
        }
        __syncthreads();
    }
    if (threadIdx.x == 0)
        out[0] = -s1[0] / (float)BATCH + REG_C * (s2[0] * 0.5f) / (float)BATCH;
}

extern "C" void kernel_launch(void* const* d_in, const int* in_sizes, int n_in,
                              void* d_out, int out_size, void* d_ws, size_t ws_size,
                              hipStream_t stream) {
    (void)in_sizes; (void)n_in; (void)out_size; (void)ws_size;
    const int*   u     = (const int*)d_in[0];
    const int*   ii    = (const int*)d_in[1];
    const int*   jj    = (const int*)d_in[2];
    const int*   rows  = (const int*)d_in[3];
    const int*   cols  = (const int*)d_in[4];
    const float* vals  = (const float*)d_in[5];
    const float* u_emb = (const float*)d_in[6];
    const float* i_emb = (const float*)d_in[7];
    const float* W1_w  = (const float*)d_in[8];
    const float* W1_b  = (const float*)d_in[9];
    const float* W2_w  = (const float*)d_in[10];
    const float* W2_b  = (const float*)d_in[11];
    float* out = (float*)d_out;

    // workspace carve-up (rows padded to N_NODES_PAD so transform tail needs no guards)
    char* p = (char*)d_ws;
    float*          ego     = (float*)p;          p += (size_t)N_NODES_PAD * EMB * 4;
    float*          wsacc   = (float*)p;          p += (size_t)N_NODES_PAD * EMB * 4;
    unsigned short* ego_bf  = (unsigned short*)p; p += (size_t)N_NODES_PAD * EMB * 2;
    unsigned int*   edge_pk = (unsigned int*)p;   p += (size_t)N_EDGES * 4;
    int*   offsets  = (int*)p;    p += (size_t)(N_NODES + 1) * 4;
    int*   bukhist  = (int*)p;    p += (size_t)NBUK * 4;
    int*   bukbase  = (int*)p;    p += (size_t)(NBUK + 1) * 4;
    int*   bukcur   = (int*)p;    p += (size_t)NBUK * 4;
    float* acc      = (float*)p;  p += (size_t)5 * BATCH * 4;
    // bucketed payload (12.8 MB) aliases wsacc (25.6 MB): dead before first edge_agg
    uint2* bucketed = (uint2*)wsacc;

    hipMemsetAsync(bukhist, 0, (size_t)NBUK * 4, stream);
    hipMemsetAsync(acc, 0, (size_t)5 * BATCH * 4, stream);

    k_init_ego<<<(N_NODES * EMB / 4 + 255) / 256, 256, 0, stream>>>(u_emb, i_emb, ego, ego_bf);
    k_buk_histo<<<256, 256, 0, stream>>>(rows, bukhist);
    k_buk_scan<<<1, 512, 0, stream>>>(bukhist, bukbase, bukcur);
    k_bucket_scatter<<<(N_EDGES + TILE_C - 1) / TILE_C, 512, 0, stream>>>(rows, cols, vals, bukcur, bucketed);
    k_bucket_sort<<<NBUK, 256, 0, stream>>>(bukbase, bucketed, edge_pk, offsets);

    // layer 0 contribution (raw ego, no normalization)
    k_batch_acc<<<BATCH * 64 / 256, 256, 0, stream>>>(ego, u, ii, jj, acc, 0);

    for (int k = 0; k < N_LAYERS; ++k) {
        k_edge_agg<<<(N_NODES + 3) / 4, 256, 0, stream>>>(offsets, edge_pk, ego_bf, wsacc);
        k_transform<<<(N_NODES + 63) / 64, 256, 0, stream>>>(wsacc, ego, ego_bf,
                                              W1_w + k * 4096, W1_b + k * 64,
                                              W2_w + k * 4096, W2_b + k * 64);
        k_batch_acc<<<BATCH * 64 / 256, 256, 0, stream>>>(ego, u, ii, jj, acc, 1);
    }
    k_finalize<<<1, 1024, 0, stream>>>(acc, out);
}

// Round 7
// 362.832 us; speedup vs baseline: 1.5815x; 1.1467x over previous
//
#include <hip/hip_runtime.h>
#include <math.h>

#define N_USERS 50000
#define N_ITEMS 50000
#define N_NODES 100000
#define N_NODES_PAD 100032
#define EMB 64
#define N_LAYERS 3
#define N_EDGES 1600000
#define BATCH 16384
#define REG_C 1e-05f
#define SLOPE 0.01f
#define EPS_C 1e-12f

// bucket sort: bucket = row >> 8 (256 rows per bucket)
#define NBUK 391                 // ceil(100000/256)
#define TILE_C 6144              // edges staged per block in k_bucket_scatter
#define SPK_MAX 4608             // per-bucket LDS capacity in k_bucket_sort (avg 4092, sigma 64)

// val quantization: val in [0, 0.05) -> 15-bit fixed point packed above 17-bit col
#define VAL_ENC 655360.0f        // 32768 / 0.05
#define VAL_DEC (1.0f / 655360.0f)

__device__ __forceinline__ unsigned short f2bf(float f) {
    unsigned int b = __float_as_uint(f);
    return (unsigned short)((b + 0x7fffu + ((b >> 16) & 1u)) >> 16);   // RNE
}

// ---------------- ego init: concat(u_emb, i_emb) + bf16 mirror ----------------
__global__ void k_init_ego(const float* __restrict__ u_emb,
                           const float* __restrict__ i_emb,
                           float* __restrict__ ego,
                           unsigned short* __restrict__ ego_bf) {
    int idx = blockIdx.x * blockDim.x + threadIdx.x;   // float4 index
    const int n4 = N_NODES * EMB / 4;
    if (idx < n4) {
        const int u4 = N_USERS * EMB / 4;
        float4 v = (idx < u4) ? ((const float4*)u_emb)[idx]
                              : ((const float4*)i_emb)[idx - u4];
        ((float4*)ego)[idx] = v;
        ushort4 h;
        h.x = f2bf(v.x); h.y = f2bf(v.y); h.z = f2bf(v.z); h.w = f2bf(v.w);
        *(ushort4*)&ego_bf[(size_t)idx * 4] = h;
    }
}

// ---------------- pass A: per-bucket histogram (LDS-staged) ----------------
__global__ __launch_bounds__(256) void k_buk_histo(const int* __restrict__ rows,
                                                   int* __restrict__ bukhist) {
    __shared__ int h[NBUK];
    for (int i = threadIdx.x; i < NBUK; i += 256) h[i] = 0;
    __syncthreads();
    int stride = gridDim.x * blockDim.x;
    for (int e = blockIdx.x * blockDim.x + threadIdx.x; e < N_EDGES; e += stride)
        atomicAdd(&h[rows[e] >> 8], 1);
    __syncthreads();
    for (int i = threadIdx.x; i < NBUK; i += 256)
        if (h[i]) atomicAdd(&bukhist[i], h[i]);
}

// ---------------- pass B: scan bucket bases ----------------
__global__ __launch_bounds__(512) void k_buk_scan(const int* __restrict__ bukhist,
                                                  int* __restrict__ bukbase,
                                                  int* __restrict__ bukcur) {
    __shared__ int s[512];
    int t = threadIdx.x;
    int v = (t < NBUK) ? bukhist[t] : 0;
    s[t] = v;
    __syncthreads();
    for (int st = 1; st < 512; st <<= 1) {
        int a = (t >= st) ? s[t - st] : 0;
        __syncthreads();
        s[t] += a;
        __syncthreads();
    }
    if (t < NBUK) { bukbase[t] = s[t] - v; bukcur[t] = s[t] - v; }
    if (t == 0) bukbase[NBUK] = N_EDGES;
}

// ---------------- pass C: LDS-staged bucket scatter (coalesced runs) ----------------
__global__ __launch_bounds__(512) void k_bucket_scatter(const int* __restrict__ rows,
                                                        const int* __restrict__ cols,
                                                        const float* __restrict__ vals,
                                                        int* __restrict__ bukcur,
                                                        uint2* __restrict__ bucketed) {
    __shared__ uint2 stage[TILE_C];
    __shared__ int hist[NBUK];
    __shared__ int lofs[NBUK];
    __shared__ int lcur[NBUK];
    __shared__ int gbase[NBUK];
    __shared__ int scan_s[512];
    int tid = threadIdx.x;
    int e0 = blockIdx.x * TILE_C;
    int n = min(TILE_C, N_EDGES - e0);

    for (int i = tid; i < NBUK; i += 512) hist[i] = 0;
    __syncthreads();
    for (int i = tid; i < n; i += 512) atomicAdd(&hist[rows[e0 + i] >> 8], 1);
    __syncthreads();
    // exclusive scan of hist
    int v = (tid < NBUK) ? hist[tid] : 0;
    scan_s[tid] = v;
    __syncthreads();
    for (int st = 1; st < 512; st <<= 1) {
        int a = (tid >= st) ? scan_s[tid - st] : 0;
        __syncthreads();
        scan_s[tid] += a;
        __syncthreads();
    }
    if (tid < NBUK) {
        int excl = scan_s[tid] - v;
        lofs[tid] = excl;
        lcur[tid] = excl;
        gbase[tid] = v ? atomicAdd(&bukcur[tid], v) : 0;   // one global atomic per bucket per block
    }
    __syncthreads();
    // bin edges into LDS, bucket-grouped
    for (int i = tid; i < n; i += 512) {
        int e = e0 + i;
        int r = rows[e];
        unsigned int q = __float2uint_rn(vals[e] * VAL_ENC);
        q = (q > 32767u) ? 32767u : q;
        unsigned int pk = (unsigned int)cols[e] | (q << 17);
        int pos = atomicAdd(&lcur[r >> 8], 1);
        stage[pos] = make_uint2(pk, (unsigned int)r);
    }
    __syncthreads();
    // contiguous run writes: element i belongs to bucket stage[i].y>>8
    for (int i = tid; i < n; i += 512) {
        uint2 w = stage[i];
        int b = w.y >> 8;
        bucketed[gbase[b] + (i - lofs[b])] = w;
    }
}

// ---------------- pass D: within-bucket sort -> final CSR (edge_pk, offsets) ----------------
__global__ __launch_bounds__(256) void k_bucket_sort(const int* __restrict__ bukbase,
                                                     const uint2* __restrict__ bucketed,
                                                     unsigned int* __restrict__ edge_pk,
                                                     int* __restrict__ offsets) {
    __shared__ int hist[256];
    __shared__ int lofs[256];
    __shared__ int lcur[256];
    __shared__ unsigned int spk[SPK_MAX];
    int b = blockIdx.x, tid = threadIdx.x;
    int s = bukbase[b], e = bukbase[b + 1];
    int cnt = e - s;
    int r0 = b << 8;
    int nrows = min(256, N_NODES - r0);

    hist[tid] = 0;
    __syncthreads();
    for (int i = tid; i < cnt; i += 256) atomicAdd(&hist[bucketed[s + i].y & 255u], 1);
    __syncthreads();
    int v = hist[tid];
    lofs[tid] = v;
    __syncthreads();
    for (int st = 1; st < 256; st <<= 1) {
        int a = (tid >= st) ? lofs[tid - st] : 0;
        __syncthreads();
        lofs[tid] += a;
        __syncthreads();
    }
    int excl = lofs[tid] - v;   // own-element read only; no race
    __syncthreads();
    lofs[tid] = excl;
    lcur[tid] = excl;
    if (tid < nrows) offsets[r0 + tid] = s + excl;
    if (b == NBUK - 1 && tid == 0) offsets[N_NODES] = N_EDGES;
    __syncthreads();

    if (cnt <= SPK_MAX) {
        for (int i = tid; i < cnt; i += 256) {
            uint2 w = bucketed[s + i];
            int p = atomicAdd(&lcur[w.y & 255u], 1);
            spk[p] = w.x;
        }
        __syncthreads();
        for (int i = tid; i < cnt; i += 256) edge_pk[s + i] = spk[i];   // coalesced
    } else {
        // overflow fallback (statistically unreachable): direct global scatter
        for (int i = tid; i < cnt; i += 256) {
            uint2 w = bucketed[s + i];
            int p = atomicAdd(&lcur[w.y & 255u], 1);
            edge_pk[s + p] = w.x;
        }
    }
}

// ---------------- per-layer: gather-based segment sum (bf16 rows) ----------------
// 2 nodes per wave. Lane split: half = lane>>5 (which node), g = (lane>>3)&3
// (edge slot), h = lane&7 (16B slot of the 128B bf16 row). One
// global_load_dwordx4 serves 8 edges (1 KB) per iteration. Meta loads are
// 8-lane same-address (HW broadcast); inactive slots use pk=0 (val 0, row 0,
// L1-resident). Per-half loop bound; exec-mask covers the tail. Reduction:
// shfl_xor 8,16 (stays within each 32-lane half), g==0 lanes store 2x float4.
__global__ __launch_bounds__(256) void k_edge_agg(const int* __restrict__ offsets,
                                                  const unsigned int* __restrict__ edge_pk,
                                                  const unsigned short* __restrict__ ego_bf,
                                                  float* __restrict__ wsacc) {
    int wid = blockIdx.x * 4 + (threadIdx.x >> 6);   // wave id: owns nodes 2w, 2w+1
    int lane = threadIdx.x & 63;
    int half = lane >> 5;
    int g = (lane >> 3) & 3;
    int h = lane & 7;
    int n = wid * 2 + half;
    if (n >= N_NODES) return;
    int o0 = offsets[n], o1 = offsets[n + 1];
    int d = o1 - o0;
    int T = (d + 3) >> 2;          // per-half bound; wave runs max via exec mask
    float a0 = 0.f, a1 = 0.f, a2 = 0.f, a3 = 0.f;
    float a4 = 0.f, a5 = 0.f, a6 = 0.f, a7 = 0.f;
    int e = o0 + g;
    unsigned int pk = (e < o1) ? edge_pk[e] : 0u;
    for (int t = 0; t < T; ++t) {
        unsigned int cur = pk;
        int en = e + 4;
        pk = (en < o1) ? edge_pk[en] : 0u;   // prefetch next meta
        int c = (int)(cur & 0x1FFFFu);
        float v = (float)(cur >> 17) * VAL_DEC;
        uint4 r = *(const uint4*)&ego_bf[(size_t)c * EMB + h * 8];
        a0 += v * __uint_as_float(r.x << 16);
        a1 += v * __uint_as_float(r.x & 0xffff0000u);
        a2 += v * __uint_as_float(r.y << 16);
        a3 += v * __uint_as_float(r.y & 0xffff0000u);
        a4 += v * __uint_as_float(r.z << 16);
        a5 += v * __uint_as_float(r.z & 0xffff0000u);
        a6 += v * __uint_as_float(r.w << 16);
        a7 += v * __uint_as_float(r.w & 0xffff0000u);
        e = en;
    }
    // reduce over the 4 edge-groups (masks 8,16 stay inside each 32-lane half)
    a0 += __shfl_xor(a0, 8, 64);  a1 += __shfl_xor(a1, 8, 64);
    a2 += __shfl_xor(a2, 8, 64);  a3 += __shfl_xor(a3, 8, 64);
    a4 += __shfl_xor(a4, 8, 64);  a5 += __shfl_xor(a5, 8, 64);
    a6 += __shfl_xor(a6, 8, 64);  a7 += __shfl_xor(a7, 8, 64);
    a0 += __shfl_xor(a0, 16, 64); a1 += __shfl_xor(a1, 16, 64);
    a2 += __shfl_xor(a2, 16, 64); a3 += __shfl_xor(a3, 16, 64);
    a4 += __shfl_xor(a4, 16, 64); a5 += __shfl_xor(a5, 16, 64);
    a6 += __shfl_xor(a6, 16, 64); a7 += __shfl_xor(a7, 16, 64);
    if (g == 0) {
        size_t base = (size_t)n * EMB + h * 8;
        *(float4*)&wsacc[base]     = make_float4(a0, a1, a2, a3);
        *(float4*)&wsacc[base + 4] = make_float4(a4, a5, a6, a7);
    }
}

// ---------------- per-layer transform: tiled f32 GEMM ----------------
// t = [ws | ws*ego] @ [W1^T ; W2^T] + b1 + b2 ; leaky-relu -> ego (+ bf16 mirror)
// BM=64 rows/block, all 64 cols, K=128 split in two 64-phases.
// __launch_bounds__(256,3): cap VGPR so the K-loop (unroll 2) cannot spill;
// LDS 48KB -> 3 blocks/CU, matching.
__global__ __launch_bounds__(256, 3) void k_transform(const float* __restrict__ wsacc,
                                                      float* __restrict__ ego,
                                                      unsigned short* __restrict__ ego_bf,
                                                      const float* __restrict__ W1,
                                                      const float* __restrict__ b1,
                                                      const float* __restrict__ W2,
                                                      const float* __restrict__ b2) {
    __shared__ float Xs[64 * 64];    // [r][k'] swizzled, one K-half at a time
    __shared__ float Ws[64 * 128];   // [c][kk'] swizzled, kk = 0..127 (W1 | W2)
    int tid = threadIdx.x;

    // stage Wcat: Ws[c][k] = W1[c][k], Ws[c][64+k] = W2[c][k]; swizzle k' = k ^ ((c>>2 & 7)<<2)
    for (int idx = tid; idx < 4096; idx += 256) {
        int c = idx >> 6, k = idx & 63;
        int s = ((c >> 2) & 7) << 2;
        Ws[c * 128 + (k ^ s)]        = W1[idx];
        Ws[c * 128 + 64 + (k ^ s)]   = W2[idx];   // (64+k)^s == 64 + (k^s)
    }

    int lane = tid & 63, wv = tid >> 6;
    int r0 = blockIdx.x * 64;
    int ty = tid >> 4;       // 0..15 : owns rows ty*4 .. ty*4+3
    int tx = tid & 15;       // 0..15 : owns cols tx*4 .. tx*4+3
    int sa = (ty & 7) << 2;  // row swizzle: (r>>2)&7 == ty&7 for r = ty*4+i
    int sb = (tx & 7) << 2;  // col-row swizzle for Ws rows c = tx*4+j

    float acc[4][4] = {};

    // ---- phase A: k = 0..63 with X = ws ----
    for (int r = wv; r < 64; r += 4) {
        float wsv = wsacc[(size_t)(r0 + r) * EMB + lane];
        int s = ((r >> 2) & 7) << 2;
        Xs[r * 64 + (lane ^ s)] = wsv;
    }
    __syncthreads();
    #pragma unroll 2
    for (int ko = 0; ko < 64; ko += 4) {
        float4 a[4], b[4];
        #pragma unroll
        for (int i = 0; i < 4; ++i)
            a[i] = *(const float4*)&Xs[(ty * 4 + i) * 64 + (ko ^ sa)];
        #pragma unroll
        for (int j = 0; j < 4; ++j)
            b[j] = *(const float4*)&Ws[(tx * 4 + j) * 128 + (ko ^ sb)];
        #pragma unroll
        for (int i = 0; i < 4; ++i)
            #pragma unroll
            for (int j = 0; j < 4; ++j)
                acc[i][j] += a[i].x * b[j].x + a[i].y * b[j].y
                           + a[i].z * b[j].z + a[i].w * b[j].w;
    }
    __syncthreads();

    // ---- phase B: k = 64..127 with X = ws*ego ----
    for (int r = wv; r < 64; r += 4) {
        size_t g = (size_t)(r0 + r) * EMB + lane;
        float v = wsacc[g] * ego[g];
        int s = ((r >> 2) & 7) << 2;
        Xs[r * 64 + (lane ^ s)] = v;
    }
    __syncthreads();
    #pragma unroll 2
    for (int ko = 0; ko < 64; ko += 4) {
        float4 a[4], b[4];
        #pragma unroll
        for (int i = 0; i < 4; ++i)
            a[i] = *(const float4*)&Xs[(ty * 4 + i) * 64 + (ko ^ sa)];
        #pragma unroll
        for (int j = 0; j < 4; ++j)
            b[j] = *(const float4*)&Ws[(tx * 4 + j) * 128 + 64 + (ko ^ sb)];
        #pragma unroll
        for (int i = 0; i < 4; ++i)
            #pragma unroll
            for (int j = 0; j < 4; ++j)
                acc[i][j] += a[i].x * b[j].x + a[i].y * b[j].y
                           + a[i].z * b[j].z + a[i].w * b[j].w;
    }

    // ---- epilogue: bias + leaky, write ego (f32) + ego_bf (bf16 mirror) ----
    float4 bb1 = *(const float4*)&b1[tx * 4];
    float4 bb2 = *(const float4*)&b2[tx * 4];
    float bias[4] = { bb1.x + bb2.x, bb1.y + bb2.y, bb1.z + bb2.z, bb1.w + bb2.w };
    #pragma unroll
    for (int i = 0; i < 4; ++i) {
        int r = r0 + ty * 4 + i;   // < N_NODES_PAD, buffer padded -> no guard
        float4 o;
        float t0 = acc[i][0] + bias[0]; o.x = (t0 >= 0.f) ? t0 : SLOPE * t0;
        float t1 = acc[i][1] + bias[1]; o.y = (t1 >= 0.f) ? t1 : SLOPE * t1;
        float t2 = acc[i][2] + bias[2]; o.z = (t2 >= 0.f) ? t2 : SLOPE * t2;
        float t3 = acc[i][3] + bias[3]; o.w = (t3 >= 0.f) ? t3 : SLOPE * t3;
        *(float4*)&ego[(size_t)r * EMB + tx * 4] = o;
        ushort4 h;
        h.x = f2bf(o.x); h.y = f2bf(o.y); h.z = f2bf(o.z); h.w = f2bf(o.w);
        *(ushort4*)&ego_bf[(size_t)r * EMB + tx * 4] = h;
    }
}

// ---------------- per-layer: batch gather + partial-loss accumulation ----------------
// acc layout: [0]=dot_up, [1]=dot_un, [2]=ssq_u, [3]=ssq_p, [4]=ssq_n ; each [BATCH]
__global__ __launch_bounds__(256) void k_batch_acc(const float* __restrict__ src,
                                                   const int* __restrict__ u,
                                                   const int* __restrict__ ii,
                                                   const int* __restrict__ jj,
                                                   float* __restrict__ acc,
                                                   int normalize) {
    int wid = (blockIdx.x * blockDim.x + threadIdx.x) >> 6;
    int lane = threadIdx.x & 63;
    if (wid >= BATCH) return;
    int nu = u[wid];
    int np_ = N_USERS + ii[wid];
    int nn = N_USERS + jj[wid];
    float eu = src[(size_t)nu * EMB + lane];
    float ep = src[(size_t)np_ * EMB + lane];
    float en = src[(size_t)nn * EMB + lane];
    float d_up = eu * ep, d_un = eu * en;
    float s_u = eu * eu, s_p = ep * ep, s_n = en * en;
    #pragma unroll
    for (int m = 32; m > 0; m >>= 1) {
        d_up += __shfl_xor(d_up, m, 64);
        d_un += __shfl_xor(d_un, m, 64);
        s_u  += __shfl_xor(s_u,  m, 64);
        s_p  += __shfl_xor(s_p,  m, 64);
        s_n  += __shfl_xor(s_n,  m, 64);
    }
    if (lane == 0) {
        if (normalize) {
            float inu = 1.f / fmaxf(sqrtf(s_u), EPS_C);
            float inp = 1.f / fmaxf(sqrtf(s_p), EPS_C);
            float inn = 1.f / fmaxf(sqrtf(s_n), EPS_C);
            d_up *= inu * inp;
            d_un *= inu * inn;
            s_u *= inu * inu;
            s_p *= inp * inp;
            s_n *= inn * inn;
        }
        acc[0 * BATCH + wid] += d_up;
        acc[1 * BATCH + wid] += d_un;
        acc[2 * BATCH + wid] += s_u;
        acc[3 * BATCH + wid] += s_p;
        acc[4 * BATCH + wid] += s_n;
    }
}

// ---------------- final scalar ----------------
__global__ __launch_bounds__(1024) void k_finalize(const float* __restrict__ acc,
                                                   float* __restrict__ out) {
    __shared__ float s1[1024], s2[1024];
    float ls = 0.f, l2 = 0.f;
    for (int b = threadIdx.x; b < BATCH; b += 1024) {
        float x = acc[0 * BATCH + b] - acc[1 * BATCH + b];
        ls += fminf(x, 0.f) - log1pf(expf(-fabsf(x)));
        l2 += acc[2 * BATCH + b] + acc[3 * BATCH + b] + acc[4 * BATCH + b];
    }
    s1[threadIdx.x] = ls; s2[threadIdx.x] = l2;
    __syncthreads();
    for (int st = 512; st > 0; st >>= 1) {
        if ((int)threadIdx.x < st) {
            s1[threadIdx.x] += s1[threadIdx.x + st];
            s2[threadIdx.x] += s2[threadIdx.x + st];
        }
        __syncthreads();
    }
    if (threadIdx.x == 0)
        out[0] = -s1[0] / (float)BATCH + REG_C * (s2[0] * 0.5f) / (float)BATCH;
}

extern "C" void kernel_launch(void* const* d_in, const int* in_sizes, int n_in,
                              void* d_out, int out_size, void* d_ws, size_t ws_size,
                              hipStream_t stream) {
    (void)in_sizes; (void)n_in; (void)out_size; (void)ws_size;
    const int*   u     = (const int*)d_in[0];
    const int*   ii    = (const int*)d_in[1];
    const int*   jj    = (const int*)d_in[2];
    const int*   rows  = (const int*)d_in[3];
    const int*   cols  = (const int*)d_in[4];
    const float* vals  = (const float*)d_in[5];
    const float* u_emb = (const float*)d_in[6];
    const float* i_emb = (const float*)d_in[7];
    const float* W1_w  = (const float*)d_in[8];
    const float* W1_b  = (const float*)d_in[9];
    const float* W2_w  = (const float*)d_in[10];
    const float* W2_b  = (const float*)d_in[11];
    float* out = (float*)d_out;

    // workspace carve-up (rows padded to N_NODES_PAD so transform tail needs no guards)
    char* p = (char*)d_ws;
    float*          ego     = (float*)p;          p += (size_t)N_NODES_PAD * EMB * 4;
    float*          wsacc   = (float*)p;          p += (size_t)N_NODES_PAD * EMB * 4;
    unsigned short* ego_bf  = (unsigned short*)p; p += (size_t)N_NODES_PAD * EMB * 2;
    unsigned int*   edge_pk = (unsigned int*)p;   p += (size_t)N_EDGES * 4;
    int*   offsets  = (int*)p;    p += (size_t)(N_NODES + 1) * 4;
    int*   bukhist  = (int*)p;    p += (size_t)NBUK * 4;
    int*   bukbase  = (int*)p;    p += (size_t)(NBUK + 1) * 4;
    int*   bukcur   = (int*)p;    p += (size_t)NBUK * 4;
    float* acc      = (float*)p;  p += (size_t)5 * BATCH * 4;
    // bucketed payload (12.8 MB) aliases wsacc (25.6 MB): dead before first edge_agg
    uint2* bucketed = (uint2*)wsacc;

    hipMemsetAsync(bukhist, 0, (size_t)NBUK * 4, stream);
    hipMemsetAsync(acc, 0, (size_t)5 * BATCH * 4, stream);

    k_init_ego<<<(N_NODES * EMB / 4 + 255) / 256, 256, 0, stream>>>(u_emb, i_emb, ego, ego_bf);
    k_buk_histo<<<256, 256, 0, stream>>>(rows, bukhist);
    k_buk_scan<<<1, 512, 0, stream>>>(bukhist, bukbase, bukcur);
    k_bucket_scatter<<<(N_EDGES + TILE_C - 1) / TILE_C, 512, 0, stream>>>(rows, cols, vals, bukcur, bucketed);
    k_bucket_sort<<<NBUK, 256, 0, stream>>>(bukbase, bucketed, edge_pk, offsets);

    // layer 0 contribution (raw ego, no normalization)
    k_batch_acc<<<BATCH * 64 / 256, 256, 0, stream>>>(ego, u, ii, jj, acc, 0);

    for (int k = 0; k < N_LAYERS; ++k) {
        // 2 nodes per wave -> 50000 waves -> 12500 blocks
        k_edge_agg<<<(N_NODES / 2 + 3) / 4, 256, 0, stream>>>(offsets, edge_pk, ego_bf, wsacc);
        k_transform<<<(N_NODES + 63) / 64, 256, 0, stream>>>(wsacc, ego, ego_bf,
                                              W1_w + k * 4096, W1_b + k * 64,
                                              W2_w + k * 4096, W2_b + k * 64);
        k_batch_acc<<<BATCH * 64 / 256, 256, 0, stream>>>(ego, u, ii, jj, acc, 1);
    }
    k_finalize<<<1, 1024, 0, stream>>>(acc, out);
}

// Round 8
// 285.862 us; speedup vs baseline: 2.0074x; 1.2693x over previous
//
#include <hip/hip_runtime.h>
#include <math.h>

#define N_USERS 50000
#define N_ITEMS 50000
#define N_NODES 100000
#define N_NODES_PAD 100032
#define EMB 64
#define N_LAYERS 3
#define N_EDGES 1600000
#define BATCH 16384
#define REG_C 1e-05f
#define SLOPE 0.01f
#define EPS_C 1e-12f

// bucket sort: bucket = row >> 8 (256 rows per bucket)
#define NBUK 391                 // ceil(100000/256)
#define TILE_C 6144              // edges staged per block in k_bucket_scatter
#define SPK_MAX 4608             // per-bucket LDS capacity in k_bucket_sort (avg 4092, sigma 64)

// val quantization: val in [0, 0.05) -> 15-bit fixed point packed above 17-bit col
#define VAL_ENC 655360.0f        // 32768 / 0.05
#define VAL_DEC (1.0f / 655360.0f)

typedef __attribute__((ext_vector_type(8))) short bf16x8;
typedef __attribute__((ext_vector_type(4))) float f32x4;

__device__ __forceinline__ unsigned short f2bf(float f) {
    unsigned int b = __float_as_uint(f);
    return (unsigned short)((b + 0x7fffu + ((b >> 16) & 1u)) >> 16);   // RNE
}
__device__ __forceinline__ unsigned int pack2bf(float a, float b) {
    return (unsigned int)f2bf(a) | ((unsigned int)f2bf(b) << 16);
}

// ---------------- ego init: concat(u_emb, i_emb) + bf16 mirror ----------------
__global__ void k_init_ego(const float* __restrict__ u_emb,
                           const float* __restrict__ i_emb,
                           float* __restrict__ ego,
                           unsigned short* __restrict__ ego_bf) {
    int idx = blockIdx.x * blockDim.x + threadIdx.x;   // float4 index
    const int n4 = N_NODES * EMB / 4;
    if (idx < n4) {
        const int u4 = N_USERS * EMB / 4;
        float4 v = (idx < u4) ? ((const float4*)u_emb)[idx]
                              : ((const float4*)i_emb)[idx - u4];
        ((float4*)ego)[idx] = v;
        ushort4 h;
        h.x = f2bf(v.x); h.y = f2bf(v.y); h.z = f2bf(v.z); h.w = f2bf(v.w);
        *(ushort4*)&ego_bf[(size_t)idx * 4] = h;
    }
}

// ---------------- pass A: per-bucket histogram (LDS-staged) ----------------
__global__ __launch_bounds__(256) void k_buk_histo(const int* __restrict__ rows,
                                                   int* __restrict__ bukhist) {
    __shared__ int h[NBUK];
    for (int i = threadIdx.x; i < NBUK; i += 256) h[i] = 0;
    __syncthreads();
    int stride = gridDim.x * blockDim.x;
    for (int e = blockIdx.x * blockDim.x + threadIdx.x; e < N_EDGES; e += stride)
        atomicAdd(&h[rows[e] >> 8], 1);
    __syncthreads();
    for (int i = threadIdx.x; i < NBUK; i += 256)
        if (h[i]) atomicAdd(&bukhist[i], h[i]);
}

// ---------------- pass B: scan bucket bases ----------------
__global__ __launch_bounds__(512) void k_buk_scan(const int* __restrict__ bukhist,
                                                  int* __restrict__ bukbase,
                                                  int* __restrict__ bukcur) {
    __shared__ int s[512];
    int t = threadIdx.x;
    int v = (t < NBUK) ? bukhist[t] : 0;
    s[t] = v;
    __syncthreads();
    for (int st = 1; st < 512; st <<= 1) {
        int a = (t >= st) ? s[t - st] : 0;
        __syncthreads();
        s[t] += a;
        __syncthreads();
    }
    if (t < NBUK) { bukbase[t] = s[t] - v; bukcur[t] = s[t] - v; }
    if (t == 0) bukbase[NBUK] = N_EDGES;
}

// ---------------- pass C: LDS-staged bucket scatter (coalesced runs) ----------------
__global__ __launch_bounds__(512) void k_bucket_scatter(const int* __restrict__ rows,
                                                        const int* __restrict__ cols,
                                                        const float* __restrict__ vals,
                                                        int* __restrict__ bukcur,
                                                        uint2* __restrict__ bucketed) {
    __shared__ uint2 stage[TILE_C];
    __shared__ int hist[NBUK];
    __shared__ int lofs[NBUK];
    __shared__ int lcur[NBUK];
    __shared__ int gbase[NBUK];
    __shared__ int scan_s[512];
    int tid = threadIdx.x;
    int e0 = blockIdx.x * TILE_C;
    int n = min(TILE_C, N_EDGES - e0);

    for (int i = tid; i < NBUK; i += 512) hist[i] = 0;
    __syncthreads();
    for (int i = tid; i < n; i += 512) atomicAdd(&hist[rows[e0 + i] >> 8], 1);
    __syncthreads();
    // exclusive scan of hist
    int v = (tid < NBUK) ? hist[tid] : 0;
    scan_s[tid] = v;
    __syncthreads();
    for (int st = 1; st < 512; st <<= 1) {
        int a = (tid >= st) ? scan_s[tid - st] : 0;
        __syncthreads();
        scan_s[tid] += a;
        __syncthreads();
    }
    if (tid < NBUK) {
        int excl = scan_s[tid] - v;
        lofs[tid] = excl;
        lcur[tid] = excl;
        gbase[tid] = v ? atomicAdd(&bukcur[tid], v) : 0;   // one global atomic per bucket per block
    }
    __syncthreads();
    // bin edges into LDS, bucket-grouped
    for (int i = tid; i < n; i += 512) {
        int e = e0 + i;
        int r = rows[e];
        unsigned int q = __float2uint_rn(vals[e] * VAL_ENC);
        q = (q > 32767u) ? 32767u : q;
        unsigned int pk = (unsigned int)cols[e] | (q << 17);
        int pos = atomicAdd(&lcur[r >> 8], 1);
        stage[pos] = make_uint2(pk, (unsigned int)r);
    }
    __syncthreads();
    // contiguous run writes: element i belongs to bucket stage[i].y>>8
    for (int i = tid; i < n; i += 512) {
        uint2 w = stage[i];
        int b = w.y >> 8;
        bucketed[gbase[b] + (i - lofs[b])] = w;
    }
}

// ---------------- pass D: within-bucket sort -> final CSR (edge_pk, offsets) ----------------
__global__ __launch_bounds__(256) void k_bucket_sort(const int* __restrict__ bukbase,
                                                     const uint2* __restrict__ bucketed,
                                                     unsigned int* __restrict__ edge_pk,
                                                     int* __restrict__ offsets) {
    __shared__ int hist[256];
    __shared__ int lofs[256];
    __shared__ int lcur[256];
    __shared__ unsigned int spk[SPK_MAX];
    int b = blockIdx.x, tid = threadIdx.x;
    int s = bukbase[b], e = bukbase[b + 1];
    int cnt = e - s;
    int r0 = b << 8;
    int nrows = min(256, N_NODES - r0);

    hist[tid] = 0;
    __syncthreads();
    for (int i = tid; i < cnt; i += 256) atomicAdd(&hist[bucketed[s + i].y & 255u], 1);
    __syncthreads();
    int v = hist[tid];
    lofs[tid] = v;
    __syncthreads();
    for (int st = 1; st < 256; st <<= 1) {
        int a = (tid >= st) ? lofs[tid - st] : 0;
        __syncthreads();
        lofs[tid] += a;
        __syncthreads();
    }
    int excl = lofs[tid] - v;   // own-element read only; no race
    __syncthreads();
    lofs[tid] = excl;
    lcur[tid] = excl;
    if (tid < nrows) offsets[r0 + tid] = s + excl;
    if (b == NBUK - 1 && tid == 0) offsets[N_NODES] = N_EDGES;
    __syncthreads();

    if (cnt <= SPK_MAX) {
        for (int i = tid; i < cnt; i += 256) {
            uint2 w = bucketed[s + i];
            int p = atomicAdd(&lcur[w.y & 255u], 1);
            spk[p] = w.x;
        }
        __syncthreads();
        for (int i = tid; i < cnt; i += 256) edge_pk[s + i] = spk[i];   // coalesced
    } else {
        // overflow fallback (statistically unreachable): direct global scatter
        for (int i = tid; i < cnt; i += 256) {
            uint2 w = bucketed[s + i];
            int p = atomicAdd(&lcur[w.y & 255u], 1);
            edge_pk[s + p] = w.x;
        }
    }
}

// ---------------- per-layer: gather-based segment sum (bf16 rows) ----------------
// 2 nodes per wave. Lane split: half = lane>>5 (which node), g = (lane>>3)&3
// (edge slot), h = lane&7 (16B slot of the 128B bf16 row). One
// global_load_dwordx4 serves 8 edges (1 KB) per iteration.
__global__ __launch_bounds__(256) void k_edge_agg(const int* __restrict__ offsets,
                                                  const unsigned int* __restrict__ edge_pk,
                                                  const unsigned short* __restrict__ ego_bf,
                                                  float* __restrict__ wsacc) {
    int wid = blockIdx.x * 4 + (threadIdx.x >> 6);   // wave id: owns nodes 2w, 2w+1
    int lane = threadIdx.x & 63;
    int half = lane >> 5;
    int g = (lane >> 3) & 3;
    int h = lane & 7;
    int n = wid * 2 + half;
    if (n >= N_NODES) return;
    int o0 = offsets[n], o1 = offsets[n + 1];
    int d = o1 - o0;
    int T = (d + 3) >> 2;          // per-half bound; wave runs max via exec mask
    float a0 = 0.f, a1 = 0.f, a2 = 0.f, a3 = 0.f;
    float a4 = 0.f, a5 = 0.f, a6 = 0.f, a7 = 0.f;
    int e = o0 + g;
    unsigned int pk = (e < o1) ? edge_pk[e] : 0u;
    for (int t = 0; t < T; ++t) {
        unsigned int cur = pk;
        int en = e + 4;
        pk = (en < o1) ? edge_pk[en] : 0u;   // prefetch next meta
        int c = (int)(cur & 0x1FFFFu);
        float v = (float)(cur >> 17) * VAL_DEC;
        uint4 r = *(const uint4*)&ego_bf[(size_t)c * EMB + h * 8];
        a0 += v * __uint_as_float(r.x << 16);
        a1 += v * __uint_as_float(r.x & 0xffff0000u);
        a2 += v * __uint_as_float(r.y << 16);
        a3 += v * __uint_as_float(r.y & 0xffff0000u);
        a4 += v * __uint_as_float(r.z << 16);
        a5 += v * __uint_as_float(r.z & 0xffff0000u);
        a6 += v * __uint_as_float(r.w << 16);
        a7 += v * __uint_as_float(r.w & 0xffff0000u);
        e = en;
    }
    // reduce over the 4 edge-groups (masks 8,16 stay inside each 32-lane half)
    a0 += __shfl_xor(a0, 8, 64);  a1 += __shfl_xor(a1, 8, 64);
    a2 += __shfl_xor(a2, 8, 64);  a3 += __shfl_xor(a3, 8, 64);
    a4 += __shfl_xor(a4, 8, 64);  a5 += __shfl_xor(a5, 8, 64);
    a6 += __shfl_xor(a6, 8, 64);  a7 += __shfl_xor(a7, 8, 64);
    a0 += __shfl_xor(a0, 16, 64); a1 += __shfl_xor(a1, 16, 64);
    a2 += __shfl_xor(a2, 16, 64); a3 += __shfl_xor(a3, 16, 64);
    a4 += __shfl_xor(a4, 16, 64); a5 += __shfl_xor(a5, 16, 64);
    a6 += __shfl_xor(a6, 16, 64); a7 += __shfl_xor(a7, 16, 64);
    if (g == 0) {
        size_t base = (size_t)n * EMB + h * 8;
        *(float4*)&wsacc[base]     = make_float4(a0, a1, a2, a3);
        *(float4*)&wsacc[base + 4] = make_float4(a4, a5, a6, a7);
    }
}

// ---------------- per-layer transform: MFMA bf16 GEMM ----------------
// t = [ws | ws*ego] @ Wcat^T + b1 + b2 ; leaky -> ego (f32) + ego_bf (bf16)
// X (64 rows x K=128) staged in LDS as bf16 with 16B-granular XOR swizzle.
// Wcat (64 out x 128 in) staged as per-fragment lane-contiguous bf16.
// 4 waves/block, each wave: 16 rows x 64 cols = 4 col-tiles x 4 k-steps
// of mfma_f32_16x16x32_bf16 (A,B both [16][K]-row-major fragments).
__global__ __launch_bounds__(256) void k_transform(const float* __restrict__ wsacc,
                                                   float* __restrict__ ego,
                                                   unsigned short* __restrict__ ego_bf,
                                                   const float* __restrict__ W1,
                                                   const float* __restrict__ b1,
                                                   const float* __restrict__ W2,
                                                   const float* __restrict__ b2) {
    __shared__ short Xs16[64 * 128];   // [row][kc^ (row&7)] in 8-elem (16B) units
    __shared__ short Wb[16 * 64 * 8];  // [frag s*4+j][lane][8]
    int tid = threadIdx.x;
    int r0 = blockIdx.x * 64;

    // ---- stage W fragments: c = j*16 + (ln&15), k = s*32 + (ln>>4)*8 + i ----
    for (int u = tid; u < 1024; u += 256) {
        int fidx = u >> 6, ln = u & 63;
        int s = fidx >> 2, j = fidx & 3;
        int c = j * 16 + (ln & 15);
        int k = s * 32 + ((ln >> 4) << 3);
        const float* Wsrc = (k < 64) ? &W1[c * 64 + k] : &W2[c * 64 + (k - 64)];
        float4 wlo = *(const float4*)Wsrc;
        float4 whi = *(const float4*)(Wsrc + 4);
        uint4 o;
        o.x = pack2bf(wlo.x, wlo.y); o.y = pack2bf(wlo.z, wlo.w);
        o.z = pack2bf(whi.x, whi.y); o.w = pack2bf(whi.z, whi.w);
        *(uint4*)&Wb[u * 8] = o;
    }

    // ---- stage X = [ws | ws*ego_bf] bf16, swizzled 16B units ----
    for (int u = tid; u < 1024; u += 256) {
        int row = u >> 4, kc = u & 15;          // kc: 16B unit (8 k's); kc<8 => ws, else aff
        size_t gbase = (size_t)(r0 + row) * EMB + ((kc & 7) << 3);
        float4 wlo = *(const float4*)&wsacc[gbase];
        float4 whi = *(const float4*)&wsacc[gbase + 4];
        float f0 = wlo.x, f1 = wlo.y, f2 = wlo.z, f3 = wlo.w;
        float f4 = whi.x, f5 = whi.y, f6 = whi.z, f7 = whi.w;
        if (kc >= 8) {
            uint4 eb = *(const uint4*)&ego_bf[gbase];
            f0 *= __uint_as_float(eb.x << 16);
            f1 *= __uint_as_float(eb.x & 0xffff0000u);
            f2 *= __uint_as_float(eb.y << 16);
            f3 *= __uint_as_float(eb.y & 0xffff0000u);
            f4 *= __uint_as_float(eb.z << 16);
            f5 *= __uint_as_float(eb.z & 0xffff0000u);
            f6 *= __uint_as_float(eb.w << 16);
            f7 *= __uint_as_float(eb.w & 0xffff0000u);
        }
        uint4 o;
        o.x = pack2bf(f0, f1); o.y = pack2bf(f2, f3);
        o.z = pack2bf(f4, f5); o.w = pack2bf(f6, f7);
        *(uint4*)&Xs16[(row * 16 + (kc ^ (row & 7))) * 8] = o;
    }
    __syncthreads();

    // ---- MFMA: wave wv covers rows wv*16..+15, all 64 cols ----
    int l = tid & 63, wv = tid >> 6;
    int arow = wv * 16 + (l & 15);              // A row this lane carries
    f32x4 acc[4];
    #pragma unroll
    for (int j = 0; j < 4; ++j) acc[j] = (f32x4){0.f, 0.f, 0.f, 0.f};
    #pragma unroll
    for (int s = 0; s < 4; ++s) {
        bf16x8 af = *(const bf16x8*)&Xs16[(arow * 16 + ((s * 4 + (l >> 4)) ^ (l & 7))) * 8];
        #pragma unroll
        for (int j = 0; j < 4; ++j) {
            bf16x8 bfr = *(const bf16x8*)&Wb[((s * 4 + j) * 64 + l) * 8];
            acc[j] = __builtin_amdgcn_mfma_f32_16x16x32_bf16(af, bfr, acc[j], 0, 0, 0);
        }
    }

    // ---- epilogue: bias + leaky, write ego f32 + ego_bf ----
    int orow = r0 + wv * 16 + ((l >> 4) << 2);  // + reg r
    int ocol = l & 15;
    #pragma unroll
    for (int j = 0; j < 4; ++j) {
        int col = j * 16 + ocol;
        float bias = b1[col] + b2[col];
        #pragma unroll
        for (int r = 0; r < 4; ++r) {
            float t = acc[j][r] + bias;
            float o = (t >= 0.f) ? t : SLOPE * t;
            size_t g = (size_t)(orow + r) * EMB + col;
            ego[g] = o;
            ego_bf[g] = f2bf(o);
        }
    }
}

// ---------------- per-layer: batch gather + partial-loss accumulation ----------------
// acc layout: [0]=dot_up, [1]=dot_un, [2]=ssq_u, [3]=ssq_p, [4]=ssq_n ; each [BATCH]
__global__ __launch_bounds__(256) void k_batch_acc(const float* __restrict__ src,
                                                   const int* __restrict__ u,
                                                   const int* __restrict__ ii,
                                                   const int* __restrict__ jj,
                                                   float* __restrict__ acc,
                                                   int normalize) {
    int wid = (blockIdx.x * blockDim.x + threadIdx.x) >> 6;
    int lane = threadIdx.x & 63;
    if (wid >= BATCH) return;
    int nu = u[wid];
    int np_ = N_USERS + ii[wid];
    int nn = N_USERS + jj[wid];
    float eu = src[(size_t)nu * EMB + lane];
    float ep = src[(size_t)np_ * EMB + lane];
    float en = src[(size_t)nn * EMB + lane];
    float d_up = eu * ep, d_un = eu * en;
    float s_u = eu * eu, s_p = ep * ep, s_n = en * en;
    #pragma unroll
    for (int m = 32; m > 0; m >>= 1) {
        d_up += __shfl_xor(d_up, m, 64);
        d_un += __shfl_xor(d_un, m, 64);
        s_u  += __shfl_xor(s_u,  m, 64);
        s_p  += __shfl_xor(s_p,  m, 64);
        s_n  += __shfl_xor(s_n,  m, 64);
    }
    if (lane == 0) {
        if (normalize) {
            float inu = 1.f / fmaxf(sqrtf(s_u), EPS_C);
            float inp = 1.f / fmaxf(sqrtf(s_p), EPS_C);
            float inn = 1.f / fmaxf(sqrtf(s_n), EPS_C);
            d_up *= inu * inp;
            d_un *= inu * inn;
            s_u *= inu * inu;
            s_p *= inp * inp;
            s_n *= inn * inn;
        }
        acc[0 * BATCH + wid] += d_up;
        acc[1 * BATCH + wid] += d_un;
        acc[2 * BATCH + wid] += s_u;
        acc[3 * BATCH + wid] += s_p;
        acc[4 * BATCH + wid] += s_n;
    }
}

// ---------------- final scalar ----------------
__global__ __launch_bounds__(1024) void k_finalize(const float* __restrict__ acc,
                                                   float* __restrict__ out) {
    __shared__ float s1[1024], s2[1024];
    float ls = 0.f, l2 = 0.f;
    for (int b = threadIdx.x; b < BATCH; b += 1024) {
        float x = acc[0 * BATCH + b] - acc[1 * BATCH + b];
        ls += fminf(x, 0.f) - log1pf(expf(-fabsf(x)));
        l2 += acc[2 * BATCH + b] + acc[3 * BATCH + b] + acc[4 * BATCH + b];
    }
    s1[threadIdx.x] = ls; s2[threadIdx.x] = l2;
    __syncthreads();
    for (int st = 512; st > 0; st >>= 1) {
        if ((int)threadIdx.x < st) {
            s1[threadIdx.x] += s1[threadIdx.x + st];
            s2[threadIdx.x] += s2[threadIdx.x + st];
        }
        __syncthreads();
    }
    if (threadIdx.x == 0)
        out[0] = -s1[0] / (float)BATCH + REG_C * (s2[0] * 0.5f) / (float)BATCH;
}

extern "C" void kernel_launch(void* const* d_in, const int* in_sizes, int n_in,
                              void* d_out, int out_size, void* d_ws, size_t ws_size,
                              hipStream_t stream) {
    (void)in_sizes; (void)n_in; (void)out_size; (void)ws_size;
    const int*   u     = (const int*)d_in[0];
    const int*   ii    = (const int*)d_in[1];
    const int*   jj    = (const int*)d_in[2];
    const int*   rows  = (const int*)d_in[3];
    const int*   cols  = (const int*)d_in[4];
    const float* vals  = (const float*)d_in[5];
    const float* u_emb = (const float*)d_in[6];
    const float* i_emb = (const float*)d_in[7];
    const float* W1_w  = (const float*)d_in[8];
    const float* W1_b  = (const float*)d_in[9];
    const float* W2_w  = (const float*)d_in[10];
    const float* W2_b  = (const float*)d_in[11];
    float* out = (float*)d_out;

    // workspace carve-up (rows padded to N_NODES_PAD so transform tail needs no guards)
    char* p = (char*)d_ws;
    float*          ego     = (float*)p;          p += (size_t)N_NODES_PAD * EMB * 4;
    float*          wsacc   = (float*)p;          p += (size_t)N_NODES_PAD * EMB * 4;
    unsigned short* ego_bf  = (unsigned short*)p; p += (size_t)N_NODES_PAD * EMB * 2;
    unsigned int*   edge_pk = (unsigned int*)p;   p += (size_t)N_EDGES * 4;
    int*   offsets  = (int*)p;    p += (size_t)(N_NODES + 1) * 4;
    int*   bukhist  = (int*)p;    p += (size_t)NBUK * 4;
    int*   bukbase  = (int*)p;    p += (size_t)(NBUK + 1) * 4;
    int*   bukcur   = (int*)p;    p += (size_t)NBUK * 4;
    float* acc      = (float*)p;  p += (size_t)5 * BATCH * 4;
    // bucketed payload (12.8 MB) aliases wsacc (25.6 MB): dead before first edge_agg
    uint2* bucketed = (uint2*)wsacc;

    hipMemsetAsync(bukhist, 0, (size_t)NBUK * 4, stream);
    hipMemsetAsync(acc, 0, (size_t)5 * BATCH * 4, stream);

    k_init_ego<<<(N_NODES * EMB / 4 + 255) / 256, 256, 0, stream>>>(u_emb, i_emb, ego, ego_bf);
    k_buk_histo<<<256, 256, 0, stream>>>(rows, bukhist);
    k_buk_scan<<<1, 512, 0, stream>>>(bukhist, bukbase, bukcur);
    k_bucket_scatter<<<(N_EDGES + TILE_C - 1) / TILE_C, 512, 0, stream>>>(rows, cols, vals, bukcur, bucketed);
    k_bucket_sort<<<NBUK, 256, 0, stream>>>(bukbase, bucketed, edge_pk, offsets);

    // layer 0 contribution (raw ego, no normalization)
    k_batch_acc<<<BATCH * 64 / 256, 256, 0, stream>>>(ego, u, ii, jj, acc, 0);

    for (int k = 0; k < N_LAYERS; ++k) {
        // 2 nodes per wave -> 50000 waves -> 12500 blocks
        k_edge_agg<<<(N_NODES / 2 + 3) / 4, 256, 0, stream>>>(offsets, edge_pk, ego_bf, wsacc);
        k_transform<<<(N_NODES + 63) / 64, 256, 0, stream>>>(wsacc, ego, ego_bf,
                                              W1_w + k * 4096, W1_b + k * 64,
                                              W2_w + k * 4096, W2_b + k * 64);
        k_batch_acc<<<BATCH * 64 / 256, 256, 0, stream>>>(ego, u, ii, jj, acc, 1);
    }
    k_finalize<<<1, 1024, 0, stream>>>(acc, out);
}